// Round 9
// baseline (372.751 us; speedup 1.0000x reference)
//
#include <hip/hip_runtime.h>
#include <hip/hip_bf16.h>

#define S_LEN 2048
#define BATCH 4
#define EMB   512
#define NH    8
#define HD    64
#define SB    (S_LEN*BATCH)   // 8192
#define E3    (3*EMB)         // 1536
#define BH    (BATCH*NH)      // 32

typedef _Float16 f16;
typedef _Float16 f16x4 __attribute__((ext_vector_type(4)));
typedef _Float16 f16x8 __attribute__((ext_vector_type(8)));
typedef float    f32x4 __attribute__((ext_vector_type(4)));

// intra-wave LDS write->read ordering fence (cross-lane): wait DS ops, pin scheduler
#define LDS_FENCE() do { asm volatile("s_waitcnt lgkmcnt(0)" ::: "memory"); \
                         __builtin_amdgcn_sched_barrier(0); } while (0)

// ---------------------------------------------------------------------------
// Kernel 0: cast query / W_in / W_out to fp16 (contiguous, vectorized)
// ---------------------------------------------------------------------------
__global__ __launch_bounds__(256) void k_cast(const float* __restrict__ q,
    const float* __restrict__ wi, const float* __restrict__ wo,
    f16* __restrict__ qh, f16* __restrict__ wih, f16* __restrict__ woh)
{
    const int NQ4 = (SB*EMB)/4, NW4 = (E3*EMB)/4, NO4 = (EMB*EMB)/4;
    const int total = NQ4 + NW4 + NO4;
    for (int i = blockIdx.x * 256 + threadIdx.x; i < total; i += gridDim.x * 256) {
        const float* src; f16* dst; int j;
        if (i < NQ4)            { src = q;  dst = qh;  j = i; }
        else if (i < NQ4 + NW4) { src = wi; dst = wih; j = i - NQ4; }
        else                    { src = wo; dst = woh; j = i - NQ4 - NW4; }
        f32x4 v = *(const f32x4*)(src + (size_t)j * 4);
        f16x4 h4;
        #pragma unroll
        for (int jj = 0; jj < 4; ++jj) h4[jj] = (f16)v[jj];
        *(f16x4*)(dst + (size_t)j * 4) = h4;
    }
}

// ---------------------------------------------------------------------------
// Kernel 1: qkv = query @ W_in^T + b_in  — fp16 MFMA GEMM, 128x128 tile, BK=64.
// Epilogue: ALL of q/k/v written coalesced in (bh, s, d) layout (Qh, Kh, Vh).
// ---------------------------------------------------------------------------
__global__ __launch_bounds__(256) void k_qkv_h(const f16* __restrict__ Ah,
    const f16* __restrict__ Bw, const float* __restrict__ bin,
    f16* __restrict__ Qh, f16* __restrict__ Kh, f16* __restrict__ Vh)
{
    __shared__ f16 As[128 * 64];   // [row][chunk], phys16B = c ^ (row&7)
    __shared__ f16 Bs[128 * 64];
    const int tid = threadIdx.x;
    const int w = tid >> 6, l = tid & 63;
    const int g = l >> 4, li = l & 15;
    const int wm = w >> 1, wn = w & 1;
    const int row0 = blockIdx.x * 128;
    const int col0 = blockIdx.y * 128;

    const int srow = tid >> 3;          // 0..31
    const int sch  = tid & 7;           // logical 16B chunk
    const f16* ga = Ah + (size_t)(row0 + srow) * EMB + sch * 8;
    const f16* gb = Bw + (size_t)(col0 + srow) * EMB + sch * 8;

    f16x8 ra[4], rb[4];
    #pragma unroll
    for (int r = 0; r < 4; ++r) {
        ra[r] = *(const f16x8*)(ga + (size_t)r * 32 * EMB);
        rb[r] = *(const f16x8*)(gb + (size_t)r * 32 * EMB);
    }

    f32x4 acc[4][4];
    const f32x4 zero = {0.f, 0.f, 0.f, 0.f};
    #pragma unroll
    for (int m = 0; m < 4; ++m)
        #pragma unroll
        for (int n = 0; n < 4; ++n) acc[m][n] = zero;

    for (int kt = 0; kt < 8; ++kt) {
        __syncthreads();
        #pragma unroll
        for (int r = 0; r < 4; ++r) {
            const int rw = srow + 32 * r;
            const int po = rw * 64 + ((sch ^ (rw & 7)) << 3);
            *(f16x8*)&As[po] = ra[r];
            *(f16x8*)&Bs[po] = rb[r];
        }
        __syncthreads();
        if (kt < 7) {
            const int kn = (kt + 1) * 64;
            #pragma unroll
            for (int r = 0; r < 4; ++r) {
                ra[r] = *(const f16x8*)(ga + kn + (size_t)r * 32 * EMB);
                rb[r] = *(const f16x8*)(gb + kn + (size_t)r * 32 * EMB);
            }
        }
        #pragma unroll
        for (int kb = 0; kb < 2; ++kb) {
            f16x8 af[4], bf[4];
            #pragma unroll
            for (int m = 0; m < 4; ++m)
                af[m] = *(const f16x8*)&As[(wm*64 + m*16 + li) * 64 +
                                           (((kb*4 + g) ^ (li & 7)) << 3)];
            #pragma unroll
            for (int n = 0; n < 4; ++n)
                bf[n] = *(const f16x8*)&Bs[(wn*64 + n*16 + li) * 64 +
                                           (((kb*4 + g) ^ (li & 7)) << 3)];
            #pragma unroll
            for (int m = 0; m < 4; ++m)
                #pragma unroll
                for (int n = 0; n < 4; ++n)
                    acc[m][n] = __builtin_amdgcn_mfma_f32_16x16x32_f16(af[m], bf[n], acc[m][n], 0, 0, 0);
        }
    }

    // epilogue: C[r = row0+wm*64+m*16+g*4+jj][col = col0+wn*64+n*16+li]; b = jj
    #pragma unroll
    for (int n = 0; n < 4; ++n) {
        const int coln  = col0 + wn*64 + n*16 + li;
        const int which = coln >> 9;
        const int h     = (coln >> 6) & 7;
        const int d     = coln & 63;
        const float bb  = bin[coln];
        f16* base = (which == 0) ? Qh : (which == 1) ? Kh : Vh;
        #pragma unroll
        for (int m = 0; m < 4; ++m) {
            const int rbase = row0 + wm*64 + m*16 + g*4;
            const int s = rbase >> 2;
            #pragma unroll
            for (int jj = 0; jj < 4; ++jj) {
                const int bh = jj * NH + h;
                base[((size_t)bh * S_LEN + s) * HD + d] = (f16)(acc[m][n][jj] + bb);
            }
        }
    }
}

// ---------------------------------------------------------------------------
// Kernel 1b: Vt(bh,d,s) = transpose of Vh(bh,s,d). Both global sides are
// 128B-contiguous per row (8 lanes x 16B per row). LDS 64x64 tile, chunk-XOR.
// ---------------------------------------------------------------------------
__global__ __launch_bounds__(256) void k_vt(const f16* __restrict__ Vh,
                                            f16* __restrict__ Vt)
{
    __shared__ f16 T[64 * 64];   // [d][s], 16B chunk c phys = c ^ (d&7)
    const int tid = threadIdx.x;
    const int l = tid & 63, w = tid >> 6;
    const int bh = blockIdx.y;
    const int s0 = blockIdx.x * 64;
    const int r8 = l >> 3;        // row-in-wave-group 0..7
    const int ch = l & 7;         // 16B chunk 0..7

    #pragma unroll
    for (int it = 0; it < 2; ++it) {
        const int srow = it * 32 + w * 8 + r8;
        f16x8 v = *(const f16x8*)&Vh[((size_t)bh * S_LEN + s0 + srow) * HD + ch * 8];
        #pragma unroll
        for (int i = 0; i < 8; ++i) {
            const int d = ch * 8 + i;
            T[d * 64 + (((srow >> 3) ^ (d & 7)) << 3) + (srow & 7)] = v[i];
        }
    }
    __syncthreads();
    #pragma unroll
    for (int it = 0; it < 2; ++it) {
        const int d = it * 32 + w * 8 + r8;
        f16x8 v = *(const f16x8*)&T[d * 64 + ((ch ^ (d & 7)) << 3)];
        *(f16x8*)&Vt[((size_t)bh * HD + d) * S_LEN + s0 + ch * 8] = v;
    }
}

// ---------------------------------------------------------------------------
// Kernel 2: fused scores+softmax+PV. QBLK=128: 512 thr = 8 waves x 16 q-rows,
// all sharing the LDS-staged K/V tiles (halves K/V re-stage traffic vs QBLK=64).
// Per-wave internals identical to the round-6/7 verified structure.
// Fixed softmax shift of 30 (scores clipped ±30) == reference softmax.
// ---------------------------------------------------------------------------
__global__ __launch_bounds__(512, 2) void k_attn(
    const f16* __restrict__ Qh, const f16* __restrict__ Kh, const f16* __restrict__ Vt,
    const float* __restrict__ rpb, float* __restrict__ att, f16* __restrict__ ctxh)
{
    __shared__ f16   KT[64*64];        // [krow][d-chunk], phys16B = c ^ (krow&7)
    __shared__ f16   VTs[64*64];       // [drow][s-chunk], phys16B = c ^ (drow&7)
    __shared__ float SBm[8][16*64];    // per-wave scores [q][k], phys16B = c ^ (q&7)
    __shared__ f16   PBm[8][16*64];    // per-wave P      [q][k], phys16B = c ^ (q&7)

    const int tid = threadIdx.x;
    const int w  = tid >> 6, l = tid & 63;
    const int g  = l >> 4, li = l & 15;
    const int l8 = l >> 3, l7 = l & 7;
    const int bx = blockIdx.x;
    const int b  = bx & 3;                 // innermost: bias-sharing blocks adjacent
    const int rt = (bx >> 2) & 15;
    const int h  = bx >> 6;
    const int bh = b * NH + h;
    const int r0 = rt * 128 + w * 16;      // wave's q-row base

    const f16* qbase = Qh + ((size_t)bh * S_LEN + r0 + li) * HD;
    const f16x8 bq0 = *(const f16x8*)(qbase + g * 8);
    const f16x8 bq1 = *(const f16x8*)(qbase + 32 + g * 8);

    // staging: each of 8 waves stages 8 rows of the 64-row tile; 1 store/lane
    const int sr  = w * 8 + l8;            // tile row (row&7 == l8)
    const int scl = (l7 ^ l8) * 8;         // pre-swizzled global col
    const f16* kg = Kh + ((size_t)bh * S_LEN + sr) * HD + scl;
    const f16* vg = Vt + ((size_t)bh * HD + sr) * S_LEN + scl;
    const int stw = w * 512 + l * 8;       // linear LDS dest (f16 units)

    const int fK0 = li * 64 + ((g ^ (li & 7)) << 3);
    const int fK1 = li * 64 + (((g + 4) ^ (li & 7)) << 3);

    float* SBw = &SBm[w][0];
    f16*   PBw = &PBm[w][0];
    const int sbr = l8 * 64 + ((l7 ^ l8) << 2);

    const float* bias0 = rpb + ((size_t)h * S_LEN + r0 + l8) * S_LEN + l7 * 4;
    const float* bias1 = bias0 + (size_t)8 * S_LEN;
    float* att0 = att + ((size_t)bh * S_LEN + r0 + l8) * S_LEN + l7 * 4;
    float* att1 = att0 + (size_t)8 * S_LEN;

    const f32x4 zero = {0.f, 0.f, 0.f, 0.f};

    // =================== PASS 1 (t = 0..31): row sums of exp(S-30) ===================
    float ls0 = 0.f, ls1 = 0.f;
    f16x8 tk = *(const f16x8*)kg;
    for (int t = 0; t < 32; ++t) {
        __syncthreads();
        *(f16x8*)&KT[stw] = tk;
        __syncthreads();
        const int tn1 = (t < 31) ? t + 1 : 31;
        tk = *(const f16x8*)(kg + (size_t)tn1 * 4096);
        #pragma unroll
        for (int half = 0; half < 2; ++half) {
            #pragma unroll
            for (int n2 = 0; n2 < 2; ++n2) {
                const int n = half * 2 + n2;
                f16x8 a0 = *(const f16x8*)&KT[n * 1024 + fK0];
                f16x8 a1 = *(const f16x8*)&KT[n * 1024 + fK1];
                f32x4 st = __builtin_amdgcn_mfma_f32_16x16x32_f16(a0, bq0, zero, 0, 0, 0);
                st = __builtin_amdgcn_mfma_f32_16x16x32_f16(a1, bq1, st, 0, 0, 0);
                *(f32x4*)&SBw[li * 64 + ((((n * 4) + g) ^ (li & 7)) << 2)] = st;
            }
            LDS_FENCE();
            #pragma unroll
            for (int i = 0; i < 2; ++i) {
                f32x4 sc = *(const f32x4*)&SBw[sbr + i * 512 + half * 32];
                f32x4 bz = *(const f32x4*)((i ? bias1 : bias0) + t * 64 + half * 32);
                float acc = 0.f;
                #pragma unroll
                for (int jj = 0; jj < 4; ++jj) {
                    float bc = fminf(fmaxf(bz[jj], -5.f), 5.f) * 0.05f;
                    float v  = sc[jj] * 0.125f + bc;
                    v = fminf(fmaxf(v, -30.f), 30.f);
                    acc += __expf(v - 30.f);
                }
                if (i) ls1 += acc; else ls0 += acc;
            }
        }
    }
    ls0 += __shfl_xor(ls0, 1); ls0 += __shfl_xor(ls0, 2); ls0 += __shfl_xor(ls0, 4);
    ls1 += __shfl_xor(ls1, 1); ls1 += __shfl_xor(ls1, 2); ls1 += __shfl_xor(ls1, 4);
    const float inv0 = 1.0f / ls0;
    const float inv1 = 1.0f / ls1;

    // =================== PASS 2 (t = 31..0): weights + PV ===================
    f32x4 o[4] = {zero, zero, zero, zero};
    tk = *(const f16x8*)(kg + (size_t)31 * 4096);
    f16x8 tv = *(const f16x8*)(vg + (size_t)31 * 64);
    for (int tt = 0; tt < 32; ++tt) {
        const int t = 31 - tt;
        __syncthreads();
        *(f16x8*)&KT[stw]  = tk;
        *(f16x8*)&VTs[stw] = tv;
        __syncthreads();
        const int tp = (t > 0) ? t - 1 : 0;
        tk = *(const f16x8*)(kg + (size_t)tp * 4096);
        tv = *(const f16x8*)(vg + (size_t)tp * 64);
        #pragma unroll
        for (int half = 0; half < 2; ++half) {
            #pragma unroll
            for (int n2 = 0; n2 < 2; ++n2) {
                const int n = half * 2 + n2;
                f16x8 a0 = *(const f16x8*)&KT[n * 1024 + fK0];
                f16x8 a1 = *(const f16x8*)&KT[n * 1024 + fK1];
                f32x4 st = __builtin_amdgcn_mfma_f32_16x16x32_f16(a0, bq0, zero, 0, 0, 0);
                st = __builtin_amdgcn_mfma_f32_16x16x32_f16(a1, bq1, st, 0, 0, 0);
                *(f32x4*)&SBw[li * 64 + ((((n * 4) + g) ^ (li & 7)) << 2)] = st;
            }
            LDS_FENCE();
            #pragma unroll
            for (int i = 0; i < 2; ++i) {
                f32x4 sc = *(const f32x4*)&SBw[sbr + i * 512 + half * 32];
                f32x4 bz = *(const f32x4*)((i ? bias1 : bias0) + t * 64 + half * 32);
                const float invi = i ? inv1 : inv0;
                f32x4 w4;
                f16x4 p4;
                #pragma unroll
                for (int jj = 0; jj < 4; ++jj) {
                    float bc = fminf(fmaxf(bz[jj], -5.f), 5.f) * 0.05f;
                    float v  = sc[jj] * 0.125f + bc;
                    v = fminf(fmaxf(v, -30.f), 30.f);
                    float wt = __expf(v - 30.f) * invi;
                    w4[jj] = wt;
                    p4[jj] = (f16)wt;
                }
                __builtin_nontemporal_store(w4,
                    (f32x4*)((i ? att1 : att0) + t * 64 + half * 32));
                *(f16x4*)&PBw[(i * 8 + l8) * 64 +
                              (((half * 4 + (l7 >> 1)) ^ l8) << 3) + ((l & 1) << 2)] = p4;
            }
        }
        LDS_FENCE();
        const f16x8 pa0 = *(const f16x8*)&PBw[fK0];
        const f16x8 pa1 = *(const f16x8*)&PBw[fK1];
        #pragma unroll
        for (int n = 0; n < 4; ++n) {
            f16x8 v0 = *(const f16x8*)&VTs[n * 1024 + fK0];
            f16x8 v1 = *(const f16x8*)&VTs[n * 1024 + fK1];
            o[n] = __builtin_amdgcn_mfma_f32_16x16x32_f16(pa0, v0, o[n], 0, 0, 0);
            o[n] = __builtin_amdgcn_mfma_f32_16x16x32_f16(pa1, v1, o[n], 0, 0, 0);
        }
    }

    // epilogue: ctxh fp16 [(s*B + b)*E + h*64 + d], clipped ±10
    #pragma unroll
    for (int n = 0; n < 4; ++n) {
        #pragma unroll
        for (int jj = 0; jj < 4; ++jj) {
            const int row = r0 + g * 4 + jj;
            float v = fminf(fmaxf(o[n][jj], -10.f), 10.f);
            ctxh[((size_t)row * BATCH + b) * EMB + h * HD + n * 16 + li] = (f16)v;
        }
    }
}

// ---------------------------------------------------------------------------
// Kernel 3: out = ctx @ W_out^T + b_out — fp16 MFMA GEMM, 128x128 tile, BK=64.
// ---------------------------------------------------------------------------
__global__ __launch_bounds__(256) void k_outproj_h(const f16* __restrict__ Ah,
    const f16* __restrict__ Bw, const float* __restrict__ bout,
    float* __restrict__ out)
{
    __shared__ f16 As[128 * 64];
    __shared__ f16 Bs[128 * 64];
    const int tid = threadIdx.x;
    const int w = tid >> 6, l = tid & 63;
    const int g = l >> 4, li = l & 15;
    const int wm = w >> 1, wn = w & 1;
    const int row0 = blockIdx.x * 128;
    const int col0 = blockIdx.y * 128;

    const int srow = tid >> 3;
    const int sch  = tid & 7;
    const f16* ga = Ah + (size_t)(row0 + srow) * EMB + sch * 8;
    const f16* gb = Bw + (size_t)(col0 + srow) * EMB + sch * 8;

    f16x8 ra[4], rb[4];
    #pragma unroll
    for (int r = 0; r < 4; ++r) {
        ra[r] = *(const f16x8*)(ga + (size_t)r * 32 * EMB);
        rb[r] = *(const f16x8*)(gb + (size_t)r * 32 * EMB);
    }

    f32x4 acc[4][4];
    const f32x4 zero = {0.f, 0.f, 0.f, 0.f};
    #pragma unroll
    for (int m = 0; m < 4; ++m)
        #pragma unroll
        for (int n = 0; n < 4; ++n) acc[m][n] = zero;

    for (int kt = 0; kt < 8; ++kt) {
        __syncthreads();
        #pragma unroll
        for (int r = 0; r < 4; ++r) {
            const int rw = srow + 32 * r;
            const int po = rw * 64 + ((sch ^ (rw & 7)) << 3);
            *(f16x8*)&As[po] = ra[r];
            *(f16x8*)&Bs[po] = rb[r];
        }
        __syncthreads();
        if (kt < 7) {
            const int kn = (kt + 1) * 64;
            #pragma unroll
            for (int r = 0; r < 4; ++r) {
                ra[r] = *(const f16x8*)(ga + kn + (size_t)r * 32 * EMB);
                rb[r] = *(const f16x8*)(gb + kn + (size_t)r * 32 * EMB);
            }
        }
        #pragma unroll
        for (int kb = 0; kb < 2; ++kb) {
            f16x8 af[4], bf[4];
            #pragma unroll
            for (int m = 0; m < 4; ++m)
                af[m] = *(const f16x8*)&As[(wm*64 + m*16 + li) * 64 +
                                           (((kb*4 + g) ^ (li & 7)) << 3)];
            #pragma unroll
            for (int n = 0; n < 4; ++n)
                bf[n] = *(const f16x8*)&Bs[(wn*64 + n*16 + li) * 64 +
                                           (((kb*4 + g) ^ (li & 7)) << 3)];
            #pragma unroll
            for (int m = 0; m < 4; ++m)
                #pragma unroll
                for (int n = 0; n < 4; ++n)
                    acc[m][n] = __builtin_amdgcn_mfma_f32_16x16x32_f16(af[m], bf[n], acc[m][n], 0, 0, 0);
        }
    }

    #pragma unroll
    for (int n = 0; n < 4; ++n) {
        const int coln = col0 + wn*64 + n*16 + li;
        const float bb = bout[coln];
        #pragma unroll
        for (int m = 0; m < 4; ++m) {
            const int rbase = row0 + wm*64 + m*16 + g*4;
            #pragma unroll
            for (int jj = 0; jj < 4; ++jj)
                out[(size_t)(rbase + jj) * EMB + coln] = acc[m][n][jj] + bb;
        }
    }
}

// ---------------------------------------------------------------------------
extern "C" void kernel_launch(void* const* d_in, const int* in_sizes, int n_in,
                              void* d_out, int out_size, void* d_ws, size_t ws_size,
                              hipStream_t stream) {
    const float* query = (const float*)d_in[0];
    // d_in[1], d_in[2] unused: reference projects q,k,v all from `query`.
    const float* rpb  = (const float*)d_in[3];
    const float* Win  = (const float*)d_in[4];
    const float* bin  = (const float*)d_in[5];
    const float* Wout = (const float*)d_in[6];
    const float* bout = (const float*)d_in[7];

    float* out = (float*)d_out;
    float* att = out + (size_t)S_LEN * BATCH * EMB;   // (B,H,S,S) fp32

    const size_t per = (size_t)BH * S_LEN * HD;       // 4,194,304 elements
    f16* Qh    = (f16*)d_ws;
    f16* Kh    = Qh + per;
    f16* Vt    = Kh + per;
    f16* AqCtx = Vt + per;            // query-f16 during qkv; ctx-f16 after attn
    f16* Winh  = AqCtx + per;
    f16* Wouth = Winh + (size_t)E3 * EMB;
    f16* Vh    = Wouth + (size_t)EMB * EMB;

    k_cast     <<<dim3(2048),            256, 0, stream>>>(query, Win, Wout, AqCtx, Winh, Wouth);
    k_qkv_h    <<<dim3(SB/128, E3/128),  256, 0, stream>>>(AqCtx, Winh, bin, Qh, Kh, Vh);
    k_vt       <<<dim3(S_LEN/64, BH),    256, 0, stream>>>(Vh, Vt);
    k_attn     <<<dim3(4 * 16 * NH),     512, 0, stream>>>(Qh, Kh, Vt, rpb, att, AqCtx);
    k_outproj_h<<<dim3(SB/128, EMB/128), 256, 0, stream>>>(AqCtx, Wouth, bout, out);
}

// Round 10
// 289.044 us; speedup vs baseline: 1.2896x; 1.2896x over previous
//
#include <hip/hip_runtime.h>
#include <hip/hip_bf16.h>

#define S_LEN 2048
#define BATCH 4
#define EMB   512
#define NH    8
#define HD    64
#define SB    (S_LEN*BATCH)   // 8192
#define E3    (3*EMB)         // 1536
#define BH    (BATCH*NH)      // 32

typedef _Float16 f16;
typedef _Float16 f16x4 __attribute__((ext_vector_type(4)));
typedef _Float16 f16x8 __attribute__((ext_vector_type(8)));
typedef float    f32x4 __attribute__((ext_vector_type(4)));

// intra-wave LDS write->read ordering fence (cross-lane): wait DS ops, pin scheduler
#define LDS_FENCE() do { asm volatile("s_waitcnt lgkmcnt(0)" ::: "memory"); \
                         __builtin_amdgcn_sched_barrier(0); } while (0)

// ---------------------------------------------------------------------------
// Kernel 0: cast query / W_in / W_out to fp16 (contiguous, vectorized)
// ---------------------------------------------------------------------------
__global__ __launch_bounds__(256) void k_cast(const float* __restrict__ q,
    const float* __restrict__ wi, const float* __restrict__ wo,
    f16* __restrict__ qh, f16* __restrict__ wih, f16* __restrict__ woh)
{
    const int NQ4 = (SB*EMB)/4, NW4 = (E3*EMB)/4, NO4 = (EMB*EMB)/4;
    const int total = NQ4 + NW4 + NO4;
    for (int i = blockIdx.x * 256 + threadIdx.x; i < total; i += gridDim.x * 256) {
        const float* src; f16* dst; int j;
        if (i < NQ4)            { src = q;  dst = qh;  j = i; }
        else if (i < NQ4 + NW4) { src = wi; dst = wih; j = i - NQ4; }
        else                    { src = wo; dst = woh; j = i - NQ4 - NW4; }
        f32x4 v = *(const f32x4*)(src + (size_t)j * 4);
        f16x4 h4;
        #pragma unroll
        for (int jj = 0; jj < 4; ++jj) h4[jj] = (f16)v[jj];
        *(f16x4*)(dst + (size_t)j * 4) = h4;
    }
}

// ---------------------------------------------------------------------------
// Kernel 1: qkv = query @ W_in^T + b_in  — fp16 MFMA GEMM, 128x128 tile, BK=64.
// Epilogue: ALL of q/k/v written coalesced in (bh, s, d) layout (Qh, Kh, Vh).
// ---------------------------------------------------------------------------
__global__ __launch_bounds__(256) void k_qkv_h(const f16* __restrict__ Ah,
    const f16* __restrict__ Bw, const float* __restrict__ bin,
    f16* __restrict__ Qh, f16* __restrict__ Kh, f16* __restrict__ Vh)
{
    __shared__ f16 As[128 * 64];   // [row][chunk], phys16B = c ^ (row&7)
    __shared__ f16 Bs[128 * 64];
    const int tid = threadIdx.x;
    const int w = tid >> 6, l = tid & 63;
    const int g = l >> 4, li = l & 15;
    const int wm = w >> 1, wn = w & 1;
    const int row0 = blockIdx.x * 128;
    const int col0 = blockIdx.y * 128;

    const int srow = tid >> 3;          // 0..31
    const int sch  = tid & 7;           // logical 16B chunk
    const f16* ga = Ah + (size_t)(row0 + srow) * EMB + sch * 8;
    const f16* gb = Bw + (size_t)(col0 + srow) * EMB + sch * 8;

    f16x8 ra[4], rb[4];
    #pragma unroll
    for (int r = 0; r < 4; ++r) {
        ra[r] = *(const f16x8*)(ga + (size_t)r * 32 * EMB);
        rb[r] = *(const f16x8*)(gb + (size_t)r * 32 * EMB);
    }

    f32x4 acc[4][4];
    const f32x4 zero = {0.f, 0.f, 0.f, 0.f};
    #pragma unroll
    for (int m = 0; m < 4; ++m)
        #pragma unroll
        for (int n = 0; n < 4; ++n) acc[m][n] = zero;

    for (int kt = 0; kt < 8; ++kt) {
        __syncthreads();
        #pragma unroll
        for (int r = 0; r < 4; ++r) {
            const int rw = srow + 32 * r;
            const int po = rw * 64 + ((sch ^ (rw & 7)) << 3);
            *(f16x8*)&As[po] = ra[r];
            *(f16x8*)&Bs[po] = rb[r];
        }
        __syncthreads();
        if (kt < 7) {
            const int kn = (kt + 1) * 64;
            #pragma unroll
            for (int r = 0; r < 4; ++r) {
                ra[r] = *(const f16x8*)(ga + kn + (size_t)r * 32 * EMB);
                rb[r] = *(const f16x8*)(gb + kn + (size_t)r * 32 * EMB);
            }
        }
        #pragma unroll
        for (int kb = 0; kb < 2; ++kb) {
            f16x8 af[4], bf[4];
            #pragma unroll
            for (int m = 0; m < 4; ++m)
                af[m] = *(const f16x8*)&As[(wm*64 + m*16 + li) * 64 +
                                           (((kb*4 + g) ^ (li & 7)) << 3)];
            #pragma unroll
            for (int n = 0; n < 4; ++n)
                bf[n] = *(const f16x8*)&Bs[(wn*64 + n*16 + li) * 64 +
                                           (((kb*4 + g) ^ (li & 7)) << 3)];
            #pragma unroll
            for (int m = 0; m < 4; ++m)
                #pragma unroll
                for (int n = 0; n < 4; ++n)
                    acc[m][n] = __builtin_amdgcn_mfma_f32_16x16x32_f16(af[m], bf[n], acc[m][n], 0, 0, 0);
        }
    }

    // epilogue: C[r = row0+wm*64+m*16+g*4+jj][col = col0+wn*64+n*16+li]; b = jj
    #pragma unroll
    for (int n = 0; n < 4; ++n) {
        const int coln  = col0 + wn*64 + n*16 + li;
        const int which = coln >> 9;
        const int h     = (coln >> 6) & 7;
        const int d     = coln & 63;
        const float bb  = bin[coln];
        f16* base = (which == 0) ? Qh : (which == 1) ? Kh : Vh;
        #pragma unroll
        for (int m = 0; m < 4; ++m) {
            const int rbase = row0 + wm*64 + m*16 + g*4;
            const int s = rbase >> 2;
            #pragma unroll
            for (int jj = 0; jj < 4; ++jj) {
                const int bh = jj * NH + h;
                base[((size_t)bh * S_LEN + s) * HD + d] = (f16)(acc[m][n][jj] + bb);
            }
        }
    }
}

// ---------------------------------------------------------------------------
// Kernel 1b: Vt(bh,d,s) = transpose of Vh(bh,s,d). Both global sides are
// 128B-contiguous per row (8 lanes x 16B per row). LDS 64x64 tile, chunk-XOR.
// ---------------------------------------------------------------------------
__global__ __launch_bounds__(256) void k_vt(const f16* __restrict__ Vh,
                                            f16* __restrict__ Vt)
{
    __shared__ f16 T[64 * 64];   // [d][s], 16B chunk c phys = c ^ (d&7)
    const int tid = threadIdx.x;
    const int l = tid & 63, w = tid >> 6;
    const int bh = blockIdx.y;
    const int s0 = blockIdx.x * 64;
    const int r8 = l >> 3;        // row-in-wave-group 0..7
    const int ch = l & 7;         // 16B chunk 0..7

    #pragma unroll
    for (int it = 0; it < 2; ++it) {
        const int srow = it * 32 + w * 8 + r8;
        f16x8 v = *(const f16x8*)&Vh[((size_t)bh * S_LEN + s0 + srow) * HD + ch * 8];
        #pragma unroll
        for (int i = 0; i < 8; ++i) {
            const int d = ch * 8 + i;
            T[d * 64 + (((srow >> 3) ^ (d & 7)) << 3) + (srow & 7)] = v[i];
        }
    }
    __syncthreads();
    #pragma unroll
    for (int it = 0; it < 2; ++it) {
        const int d = it * 32 + w * 8 + r8;
        f16x8 v = *(const f16x8*)&T[d * 64 + ((ch ^ (d & 7)) << 3)];
        *(f16x8*)&Vt[((size_t)bh * HD + d) * S_LEN + s0 + ch * 8] = v;
    }
}

// ---------------------------------------------------------------------------
// Kernel 2: fused scores+softmax+PV (round-8 verified structure, QBLK=64,
// 4 waves, 4 blocks/CU) + BIAS REGISTER PREFETCH: tile t+1's bias is loaded
// right after the staging barrier, before the MFMA/fence region, so its
// latency hides under tile-t compute (sched_barrier previously pinned these
// loads below the fence, exposing full latency per half-tile).
// Fixed softmax shift of 30 (scores clipped ±30) == reference softmax.
// ---------------------------------------------------------------------------
__global__ __launch_bounds__(256, 4) void k_attn(
    const f16* __restrict__ Qh, const f16* __restrict__ Kh, const f16* __restrict__ Vt,
    const float* __restrict__ rpb, float* __restrict__ att, f16* __restrict__ ctxh)
{
    __shared__ f16   KT[64*64];        // [krow][d-chunk], phys16B = c ^ (krow&7)
    __shared__ f16   VTs[64*64];       // [drow][s-chunk], phys16B = c ^ (drow&7)
    __shared__ float SBm[4][16*64];    // per-wave scores [q][k], phys16B = c ^ (q&7)
    __shared__ f16   PBm[4][16*64];    // per-wave P      [q][k], phys16B = c ^ (q&7)

    const int tid = threadIdx.x;
    const int w  = tid >> 6, l = tid & 63;
    const int g  = l >> 4, li = l & 15;
    const int l8 = l >> 3, l7 = l & 7;
    const int bx = blockIdx.x;
    const int b  = bx & 3;
    const int rt = (bx >> 2) & 31;
    const int h  = bx >> 7;
    const int bh = b * NH + h;
    const int r0 = rt * 64 + w * 16;

    const f16* qbase = Qh + ((size_t)bh * S_LEN + r0 + li) * HD;
    const f16x8 bq0 = *(const f16x8*)(qbase + g * 8);
    const f16x8 bq1 = *(const f16x8*)(qbase + 32 + g * 8);

    const int sr0 = w * 16 + l8;
    const int sr1 = sr0 + 8;
    const int scl = (l7 ^ l8) * 8;
    const f16* kg0 = Kh + ((size_t)bh * S_LEN + sr0) * HD + scl;
    const f16* kg1 = Kh + ((size_t)bh * S_LEN + sr1) * HD + scl;
    const f16* vg0 = Vt + ((size_t)bh * HD + sr0) * S_LEN + scl;
    const f16* vg1 = Vt + ((size_t)bh * HD + sr1) * S_LEN + scl;
    const int stw0 = (w * 2 + 0) * 512 + l * 8;
    const int stw1 = (w * 2 + 1) * 512 + l * 8;

    const int fK0 = li * 64 + ((g ^ (li & 7)) << 3);
    const int fK1 = li * 64 + (((g + 4) ^ (li & 7)) << 3);

    float* SBw = &SBm[w][0];
    f16*   PBw = &PBm[w][0];
    const int sbr = l8 * 64 + ((l7 ^ l8) << 2);

    const float* bias0 = rpb + ((size_t)h * S_LEN + r0 + l8) * S_LEN + l7 * 4;
    const float* bias1 = bias0 + (size_t)8 * S_LEN;
    float* att0 = att + ((size_t)bh * S_LEN + r0 + l8) * S_LEN + l7 * 4;
    float* att1 = att0 + (size_t)8 * S_LEN;

    const f32x4 zero = {0.f, 0.f, 0.f, 0.f};

    // =================== PASS 1 (t = 0..31): row sums of exp(S-30) ===================
    float ls0 = 0.f, ls1 = 0.f;
    f16x8 tk0 = *(const f16x8*)kg0;
    f16x8 tk1 = *(const f16x8*)kg1;
    f32x4 bzn[2][2], bzc[2][2];        // [i(row-block)][half] bias prefetch regs
    #pragma unroll
    for (int i = 0; i < 2; ++i) {
        bzn[i][0] = *(const f32x4*)((i ? bias1 : bias0));
        bzn[i][1] = *(const f32x4*)((i ? bias1 : bias0) + 32);
    }
    for (int t = 0; t < 32; ++t) {
        __syncthreads();
        *(f16x8*)&KT[stw0] = tk0;
        *(f16x8*)&KT[stw1] = tk1;
        __syncthreads();
        const int tn1 = (t < 31) ? t + 1 : 31;
        tk0 = *(const f16x8*)(kg0 + (size_t)tn1 * 4096);
        tk1 = *(const f16x8*)(kg1 + (size_t)tn1 * 4096);
        #pragma unroll
        for (int i = 0; i < 2; ++i) {
            bzc[i][0] = bzn[i][0];
            bzc[i][1] = bzn[i][1];
        }
        #pragma unroll
        for (int i = 0; i < 2; ++i) {      // issue t+1 bias loads pre-fence
            bzn[i][0] = *(const f32x4*)((i ? bias1 : bias0) + (size_t)tn1 * 64);
            bzn[i][1] = *(const f32x4*)((i ? bias1 : bias0) + (size_t)tn1 * 64 + 32);
        }
        #pragma unroll
        for (int half = 0; half < 2; ++half) {
            #pragma unroll
            for (int n2 = 0; n2 < 2; ++n2) {
                const int n = half * 2 + n2;
                f16x8 a0 = *(const f16x8*)&KT[n * 1024 + fK0];
                f16x8 a1 = *(const f16x8*)&KT[n * 1024 + fK1];
                f32x4 st = __builtin_amdgcn_mfma_f32_16x16x32_f16(a0, bq0, zero, 0, 0, 0);
                st = __builtin_amdgcn_mfma_f32_16x16x32_f16(a1, bq1, st, 0, 0, 0);
                *(f32x4*)&SBw[li * 64 + ((((n * 4) + g) ^ (li & 7)) << 2)] = st;
            }
            LDS_FENCE();
            #pragma unroll
            for (int i = 0; i < 2; ++i) {
                f32x4 sc = *(const f32x4*)&SBw[sbr + i * 512 + half * 32];
                float acc = 0.f;
                #pragma unroll
                for (int jj = 0; jj < 4; ++jj) {
                    float bc = fminf(fmaxf(bzc[i][half][jj], -5.f), 5.f) * 0.05f;
                    float v  = sc[jj] * 0.125f + bc;
                    v = fminf(fmaxf(v, -30.f), 30.f);
                    acc += __expf(v - 30.f);
                }
                if (i) ls1 += acc; else ls0 += acc;
            }
        }
    }
    ls0 += __shfl_xor(ls0, 1); ls0 += __shfl_xor(ls0, 2); ls0 += __shfl_xor(ls0, 4);
    ls1 += __shfl_xor(ls1, 1); ls1 += __shfl_xor(ls1, 2); ls1 += __shfl_xor(ls1, 4);
    const float inv0 = 1.0f / ls0;
    const float inv1 = 1.0f / ls1;

    // =================== PASS 2 (t = 31..0, L3-warm bias): weights + PV ===============
    f32x4 o[4] = {zero, zero, zero, zero};
    tk0 = *(const f16x8*)(kg0 + (size_t)31 * 4096);
    tk1 = *(const f16x8*)(kg1 + (size_t)31 * 4096);
    f16x8 tv0 = *(const f16x8*)(vg0 + (size_t)31 * 64);
    f16x8 tv1 = *(const f16x8*)(vg1 + (size_t)31 * 64);
    #pragma unroll
    for (int i = 0; i < 2; ++i) {
        bzn[i][0] = *(const f32x4*)((i ? bias1 : bias0) + (size_t)31 * 64);
        bzn[i][1] = *(const f32x4*)((i ? bias1 : bias0) + (size_t)31 * 64 + 32);
    }
    for (int tt = 0; tt < 32; ++tt) {
        const int t = 31 - tt;
        __syncthreads();
        *(f16x8*)&KT[stw0]  = tk0;
        *(f16x8*)&KT[stw1]  = tk1;
        *(f16x8*)&VTs[stw0] = tv0;
        *(f16x8*)&VTs[stw1] = tv1;
        __syncthreads();
        const int tp = (t > 0) ? t - 1 : 0;
        tk0 = *(const f16x8*)(kg0 + (size_t)tp * 4096);
        tk1 = *(const f16x8*)(kg1 + (size_t)tp * 4096);
        tv0 = *(const f16x8*)(vg0 + (size_t)tp * 64);
        tv1 = *(const f16x8*)(vg1 + (size_t)tp * 64);
        #pragma unroll
        for (int i = 0; i < 2; ++i) {
            bzc[i][0] = bzn[i][0];
            bzc[i][1] = bzn[i][1];
        }
        #pragma unroll
        for (int i = 0; i < 2; ++i) {      // issue t-1 bias loads pre-fence
            bzn[i][0] = *(const f32x4*)((i ? bias1 : bias0) + (size_t)tp * 64);
            bzn[i][1] = *(const f32x4*)((i ? bias1 : bias0) + (size_t)tp * 64 + 32);
        }
        #pragma unroll
        for (int half = 0; half < 2; ++half) {
            #pragma unroll
            for (int n2 = 0; n2 < 2; ++n2) {
                const int n = half * 2 + n2;
                f16x8 a0 = *(const f16x8*)&KT[n * 1024 + fK0];
                f16x8 a1 = *(const f16x8*)&KT[n * 1024 + fK1];
                f32x4 st = __builtin_amdgcn_mfma_f32_16x16x32_f16(a0, bq0, zero, 0, 0, 0);
                st = __builtin_amdgcn_mfma_f32_16x16x32_f16(a1, bq1, st, 0, 0, 0);
                *(f32x4*)&SBw[li * 64 + ((((n * 4) + g) ^ (li & 7)) << 2)] = st;
            }
            LDS_FENCE();
            #pragma unroll
            for (int i = 0; i < 2; ++i) {
                f32x4 sc = *(const f32x4*)&SBw[sbr + i * 512 + half * 32];
                const float invi = i ? inv1 : inv0;
                f32x4 w4;
                f16x4 p4;
                #pragma unroll
                for (int jj = 0; jj < 4; ++jj) {
                    float bc = fminf(fmaxf(bzc[i][half][jj], -5.f), 5.f) * 0.05f;
                    float v  = sc[jj] * 0.125f + bc;
                    v = fminf(fmaxf(v, -30.f), 30.f);
                    float wt = __expf(v - 30.f) * invi;
                    w4[jj] = wt;
                    p4[jj] = (f16)wt;
                }
                __builtin_nontemporal_store(w4,
                    (f32x4*)((i ? att1 : att0) + (size_t)t * 64 + half * 32));
                *(f16x4*)&PBw[(i * 8 + l8) * 64 +
                              (((half * 4 + (l7 >> 1)) ^ l8) << 3) + ((l & 1) << 2)] = p4;
            }
        }
        LDS_FENCE();
        const f16x8 pa0 = *(const f16x8*)&PBw[fK0];
        const f16x8 pa1 = *(const f16x8*)&PBw[fK1];
        #pragma unroll
        for (int n = 0; n < 4; ++n) {
            f16x8 v0 = *(const f16x8*)&VTs[n * 1024 + fK0];
            f16x8 v1 = *(const f16x8*)&VTs[n * 1024 + fK1];
            o[n] = __builtin_amdgcn_mfma_f32_16x16x32_f16(pa0, v0, o[n], 0, 0, 0);
            o[n] = __builtin_amdgcn_mfma_f32_16x16x32_f16(pa1, v1, o[n], 0, 0, 0);
        }
    }

    // epilogue: ctxh fp16 [(s*B + b)*E + h*64 + d], clipped ±10
    #pragma unroll
    for (int n = 0; n < 4; ++n) {
        #pragma unroll
        for (int jj = 0; jj < 4; ++jj) {
            const int row = r0 + g * 4 + jj;
            float v = fminf(fmaxf(o[n][jj], -10.f), 10.f);
            ctxh[((size_t)row * BATCH + b) * EMB + h * HD + n * 16 + li] = (f16)v;
        }
    }
}

// ---------------------------------------------------------------------------
// Kernel 3: out = ctx @ W_out^T + b_out — fp16 MFMA GEMM, 128x128 tile, BK=64.
// ---------------------------------------------------------------------------
__global__ __launch_bounds__(256) void k_outproj_h(const f16* __restrict__ Ah,
    const f16* __restrict__ Bw, const float* __restrict__ bout,
    float* __restrict__ out)
{
    __shared__ f16 As[128 * 64];
    __shared__ f16 Bs[128 * 64];
    const int tid = threadIdx.x;
    const int w = tid >> 6, l = tid & 63;
    const int g = l >> 4, li = l & 15;
    const int wm = w >> 1, wn = w & 1;
    const int row0 = blockIdx.x * 128;
    const int col0 = blockIdx.y * 128;

    const int srow = tid >> 3;
    const int sch  = tid & 7;
    const f16* ga = Ah + (size_t)(row0 + srow) * EMB + sch * 8;
    const f16* gb = Bw + (size_t)(col0 + srow) * EMB + sch * 8;

    f16x8 ra[4], rb[4];
    #pragma unroll
    for (int r = 0; r < 4; ++r) {
        ra[r] = *(const f16x8*)(ga + (size_t)r * 32 * EMB);
        rb[r] = *(const f16x8*)(gb + (size_t)r * 32 * EMB);
    }

    f32x4 acc[4][4];
    const f32x4 zero = {0.f, 0.f, 0.f, 0.f};
    #pragma unroll
    for (int m = 0; m < 4; ++m)
        #pragma unroll
        for (int n = 0; n < 4; ++n) acc[m][n] = zero;

    for (int kt = 0; kt < 8; ++kt) {
        __syncthreads();
        #pragma unroll
        for (int r = 0; r < 4; ++r) {
            const int rw = srow + 32 * r;
            const int po = rw * 64 + ((sch ^ (rw & 7)) << 3);
            *(f16x8*)&As[po] = ra[r];
            *(f16x8*)&Bs[po] = rb[r];
        }
        __syncthreads();
        if (kt < 7) {
            const int kn = (kt + 1) * 64;
            #pragma unroll
            for (int r = 0; r < 4; ++r) {
                ra[r] = *(const f16x8*)(ga + kn + (size_t)r * 32 * EMB);
                rb[r] = *(const f16x8*)(gb + kn + (size_t)r * 32 * EMB);
            }
        }
        #pragma unroll
        for (int kb = 0; kb < 2; ++kb) {
            f16x8 af[4], bf[4];
            #pragma unroll
            for (int m = 0; m < 4; ++m)
                af[m] = *(const f16x8*)&As[(wm*64 + m*16 + li) * 64 +
                                           (((kb*4 + g) ^ (li & 7)) << 3)];
            #pragma unroll
            for (int n = 0; n < 4; ++n)
                bf[n] = *(const f16x8*)&Bs[(wn*64 + n*16 + li) * 64 +
                                           (((kb*4 + g) ^ (li & 7)) << 3)];
            #pragma unroll
            for (int m = 0; m < 4; ++m)
                #pragma unroll
                for (int n = 0; n < 4; ++n)
                    acc[m][n] = __builtin_amdgcn_mfma_f32_16x16x32_f16(af[m], bf[n], acc[m][n], 0, 0, 0);
        }
    }

    #pragma unroll
    for (int n = 0; n < 4; ++n) {
        const int coln = col0 + wn*64 + n*16 + li;
        const float bb = bout[coln];
        #pragma unroll
        for (int m = 0; m < 4; ++m) {
            const int rbase = row0 + wm*64 + m*16 + g*4;
            #pragma unroll
            for (int jj = 0; jj < 4; ++jj)
                out[(size_t)(rbase + jj) * EMB + coln] = acc[m][n][jj] + bb;
        }
    }
}

// ---------------------------------------------------------------------------
extern "C" void kernel_launch(void* const* d_in, const int* in_sizes, int n_in,
                              void* d_out, int out_size, void* d_ws, size_t ws_size,
                              hipStream_t stream) {
    const float* query = (const float*)d_in[0];
    // d_in[1], d_in[2] unused: reference projects q,k,v all from `query`.
    const float* rpb  = (const float*)d_in[3];
    const float* Win  = (const float*)d_in[4];
    const float* bin  = (const float*)d_in[5];
    const float* Wout = (const float*)d_in[6];
    const float* bout = (const float*)d_in[7];

    float* out = (float*)d_out;
    float* att = out + (size_t)S_LEN * BATCH * EMB;   // (B,H,S,S) fp32

    const size_t per = (size_t)BH * S_LEN * HD;       // 4,194,304 elements
    f16* Qh    = (f16*)d_ws;
    f16* Kh    = Qh + per;
    f16* Vt    = Kh + per;
    f16* AqCtx = Vt + per;            // query-f16 during qkv; ctx-f16 after attn
    f16* Winh  = AqCtx + per;
    f16* Wouth = Winh + (size_t)E3 * EMB;
    f16* Vh    = Wouth + (size_t)EMB * EMB;

    k_cast     <<<dim3(2048),            256, 0, stream>>>(query, Win, Wout, AqCtx, Winh, Wouth);
    k_qkv_h    <<<dim3(SB/128, E3/128),  256, 0, stream>>>(AqCtx, Winh, bin, Qh, Kh, Vh);
    k_vt       <<<dim3(S_LEN/64, BH),    256, 0, stream>>>(Vh, Vt);
    k_attn     <<<dim3(4 * 32 * NH),     256, 0, stream>>>(Qh, Kh, Vt, rpb, att, AqCtx);
    k_outproj_h<<<dim3(SB/128, EMB/128), 256, 0, stream>>>(AqCtx, Wouth, bout, out);
}